// Round 6
// baseline (161.516 us; speedup 1.0000x reference)
//
#include <hip/hip_runtime.h>
#include <math.h>

#define BB 4
#define CC 128
#define HF 128
#define WF 128
#define NBUCK_Y 160                  // y0+3 clamped to [0,159]
#define NBUCK (BB * NBUCK_Y)         // 640
#define PTS_PER_HBLK 2048            // points per setup/scatter block (512 thr x 4)
#define NBLK 392                     // ceil(800000/2048)=391, padded to 392
#define SCAN_M (NBUCK * NBLK)        // 250,880 = 245*1024
#define NCHUNK 245
#define GATHER_NB 2048               // persistent gather grid (multiple of 8)

typedef float f4 __attribute__((ext_vector_type(4)));

// ---------- helpers with fp-contract OFF to bit-match the numpy reference ----------
__device__ __forceinline__ float wsum3(float a, float wa, float b, float wb, float c, float wc) {
#pragma clang fp contract(off)
    {
        float r = a * wa;
        r = r + b * wb;
        r = r + c * wc;
        return r;
    }
}

__device__ __forceinline__ float to_pix(float cv, int Wm1, int WFm1) {
#pragma clang fp contract(off)
    {
        float g = cv / (float)Wm1 * 2.0f - 1.0f;
        return (g + 1.0f) * 0.5f * (float)WFm1;
    }
}

__device__ __forceinline__ int bucket_of(int b, int y0i) {
    return b * NBUCK_Y + min(max(y0i + 3, 0), NBUCK_Y - 1);
}

// ---------- 1. NCHW -> NHWC transpose of feature_map, fused with depth init ----------
__global__ void transpose_fm(const float* __restrict__ fm, float* __restrict__ fmT,
                             float* __restrict__ depth) {
    __shared__ float tile[32][33];
    int b = blockIdx.z;
    int hw0 = blockIdx.x * 32;
    int c0 = blockIdx.y * 32;
    int tx = threadIdx.x;
    int ty = threadIdx.y;
    // fused depth-buffer init: 8192 blocks x 256 threads cover the 1,048,576 texels
    int gid = (((blockIdx.z * gridDim.y + blockIdx.y) * gridDim.x + blockIdx.x) << 8) +
              (ty << 5) + tx;
    if (gid < BB * 512 * 512) depth[gid] = INFINITY;
    const float* in = fm + (size_t)b * CC * HF * WF;
    float* out = fmT + (size_t)b * HF * WF * CC;
    #pragma unroll
    for (int i = ty; i < 32; i += 8)
        tile[i][tx] = in[(size_t)(c0 + i) * (HF * WF) + hw0 + tx];
    __syncthreads();
    #pragma unroll
    for (int i = ty; i < 32; i += 8)
        out[(size_t)(hw0 + i) * CC + c0 + tx] = tile[tx][i];
}

// ---------- 2. scatter-min of vertex depths ----------
__global__ void depth_scatter(const float* __restrict__ v2d, const float* __restrict__ v3d,
                              float* __restrict__ depth, int Nv, const int* pH, const int* pW) {
    int H = *pH, W = *pW;
    int i = blockIdx.x * blockDim.x + threadIdx.x;
    if (i >= BB * Nv) return;
    int b = i / Nv, v = i - b * Nv;
    float x = v2d[((size_t)b * Nv + v) * 2 + 0];
    float y = v2d[((size_t)b * Nv + v) * 2 + 1];
    int xv = (int)rintf(x);
    int yv = (int)rintf(y);
    if (xv < 0 || xv >= W || yv < 0 || yv >= H) return;
    float z = v3d[((size_t)b * Nv + v) * 3 + 2];
    // z > 0 always, inf init: int compare == float compare for non-negative floats
    atomicMin((int*)&depth[(size_t)b * H * W + (size_t)yv * W + xv], __float_as_int(z));
}

// ---------- 3. fused per-point setup + per-block LDS histogram ----------
__global__ void __launch_bounds__(512)
setup_hist(const float* __restrict__ v2d, const float* __restrict__ v3d,
           const int* __restrict__ parents, const float* __restrict__ bary,
           const float* __restrict__ depth,
           float* __restrict__ out_vw, float* __restrict__ out_c3,
           float4* __restrict__ params, int* __restrict__ counts,
           int N, int Nv, int K, const int* pH, const int* pW) {
    __shared__ int h[NBUCK];  // 2.5 KB
    int tid = threadIdx.x;
    int blk = blockIdx.x;
    for (int t = tid; t < NBUCK; t += 512) h[t] = 0;
    __syncthreads();
    int H = *pH, W = *pW;
    #pragma unroll 1
    for (int i = 0; i < PTS_PER_HBLK / 512; i++) {
        int idx = blk * PTS_PER_HBLK + i * 512 + tid;
        if (idx >= BB * N) break;
        int b = idx / N, n = idx - b * N;
        int k = n % K;
        float w0 = bary[k * 3 + 0], w1 = bary[k * 3 + 1], w2 = bary[k * 3 + 2];
        int i0 = parents[(size_t)n * 3 + 0];
        int i1 = parents[(size_t)n * 3 + 1];
        int i2 = parents[(size_t)n * 3 + 2];
        const float* v2b = v2d + (size_t)b * Nv * 2;
        const float* v3b = v3d + (size_t)b * Nv * 3;
        float ax = v2b[(size_t)i0 * 2], ay = v2b[(size_t)i0 * 2 + 1];
        float bx = v2b[(size_t)i1 * 2], by = v2b[(size_t)i1 * 2 + 1];
        float cx = v2b[(size_t)i2 * 2], cy = v2b[(size_t)i2 * 2 + 1];
        float c2x = wsum3(ax, w0, bx, w1, cx, w2);
        float c2y = wsum3(ay, w0, by, w1, cy, w2);
        float a0 = v3b[(size_t)i0 * 3], a1 = v3b[(size_t)i0 * 3 + 1], a2 = v3b[(size_t)i0 * 3 + 2];
        float b0 = v3b[(size_t)i1 * 3], b1 = v3b[(size_t)i1 * 3 + 1], b2 = v3b[(size_t)i1 * 3 + 2];
        float c0 = v3b[(size_t)i2 * 3], c1 = v3b[(size_t)i2 * 3 + 1], c2 = v3b[(size_t)i2 * 3 + 2];
        float c3x = wsum3(a0, w0, b0, w1, c0, w2);
        float c3y = wsum3(a1, w0, b1, w1, c1, w2);
        float c3z = wsum3(a2, w0, b2, w1, c2, w2);
        float e1x = b0 - a0, e1y = b1 - a1, e1z = b2 - a2;
        float e2x = c0 - a0, e2y = c1 - a1, e2z = c2 - a2;
        float nx = e1y * e2z - e1z * e2y;
        float ny = e1z * e2x - e1x * e2z;
        float nz = e1x * e2y - e1y * e2x;
        float nn = sqrtf(nx * nx + ny * ny + nz * nz) + 1e-8f;
        nx /= nn; ny /= nn; nz /= nn;
        float vn = sqrtf(c3x * c3x + c3y * c3y + c3z * c3z) + 1e-8f;
        float vx = -c3x / vn, vy = -c3y / vn, vz = -c3z / vn;
        float ang = fmaxf(nx * vx + ny * vy + nz * vz, 0.0f);
        int xc = (int)rintf(c2x); xc = min(max(xc, 0), W - 1);
        int yc = (int)rintf(c2y); yc = min(max(yc, 0), H - 1);
        float dsamp = depth[(size_t)b * H * W + (size_t)yc * W + xc];
        bool visible = (c3z <= dsamp + 1e-3f) || isinf(dsamp);
        out_vw[idx] = visible ? ang : 0.0f;
        out_c3[(size_t)idx * 3 + 0] = c3x;
        out_c3[(size_t)idx * 3 + 1] = c3y;
        out_c3[(size_t)idx * 3 + 2] = c3z;
        float px = to_pix(c2x, W - 1, WF - 1);
        float py = to_pix(c2y, H - 1, HF - 1);
        float x0f = floorf(px), y0f = floorf(py);
        int x0i = (int)x0f, y0i = (int)y0f;
        float4 p;
        p.x = __int_as_float(x0i);
        p.y = __int_as_float(y0i);
        p.z = px - x0f;
        p.w = py - y0f;
        params[idx] = p;
        atomicAdd(&h[bucket_of(b, y0i)], 1);
    }
    __syncthreads();
    for (int t = tid; t < NBUCK; t += 512)
        counts[t * NBLK + blk] = h[t];
}

// ---------- 4. hierarchical exclusive scan over counts (in place) ----------
__global__ void scan1(int* __restrict__ counts, int* __restrict__ sums) {
    __shared__ int s[1024];
    int tid = threadIdx.x;
    int gid = blockIdx.x * 1024 + tid;
    int v = counts[gid];
    s[tid] = v;
    __syncthreads();
    #pragma unroll
    for (int d = 1; d < 1024; d <<= 1) {
        int t = (tid >= d) ? s[tid - d] : 0;
        __syncthreads();
        s[tid] += t;
        __syncthreads();
    }
    counts[gid] = s[tid] - v;             // exclusive within chunk
    if (tid == 1023) sums[blockIdx.x] = s[1023];
}

// scan3: add chunk base; base computed with a parallel LDS tree reduction
__global__ void scan3(int* __restrict__ counts, const int* __restrict__ sums) {
    __shared__ int red[256];
    int tid = threadIdx.x;
    if (tid < 256) red[tid] = (tid < blockIdx.x && tid < NCHUNK) ? sums[tid] : 0;
    __syncthreads();
    #pragma unroll
    for (int d = 128; d > 0; d >>= 1) {
        if (tid < d) red[tid] += red[tid + d];
        __syncthreads();
    }
    int gid = blockIdx.x * 1024 + tid;
    counts[gid] += red[0];
}

// ---------- 5. scatter into sorted, fully-packed records (LDS atomics only) ----------
__global__ void __launch_bounds__(512)
scatter_sorted(const float4* __restrict__ params, const int* __restrict__ scan,
               float4* __restrict__ sorted, int N) {
    __shared__ int cur[NBUCK];  // 2.5 KB
    int tid = threadIdx.x;
    int blk = blockIdx.x;
    for (int t = tid; t < NBUCK; t += 512)
        cur[t] = scan[t * NBLK + blk];
    __syncthreads();
    #pragma unroll 1
    for (int i = 0; i < PTS_PER_HBLK / 512; i++) {
        int idx = blk * PTS_PER_HBLK + i * 512 + tid;
        if (idx >= BB * N) break;
        float4 p = params[idx];
        int x0i = __float_as_int(p.x);
        int y0i = __float_as_int(p.y);
        int bu = bucket_of(idx / N, y0i);
        int pos = atomicAdd(&cur[bu], 1);
        int xs = min(max(x0i + 8, 0), 65535);
        int ys = min(max(y0i + 8, 0), 65535);
        float4 rec;
        rec.x = __int_as_float((ys << 16) | xs);
        rec.y = p.z;   // wx
        rec.z = p.w;   // wy
        rec.w = __int_as_float(idx);
        sorted[pos] = rec;
    }
}

// ---------- 6. persistent bilinear gather: XCD-chunked spans, branchless, nt stores ----------
__global__ void __launch_bounds__(256)
gather_feats(const float* __restrict__ fmT, const float4* __restrict__ sorted,
             float* __restrict__ out, int N) {
    // bijective chunk swizzle (gridDim.x % 8 == 0): consecutive spans -> same XCD
    int q = GATHER_NB >> 3;
    int xcd = blockIdx.x & 7, off = blockIdx.x >> 3;
    int nbid = xcd * q + off;
    int total = BB * N;
    int span = (total + GATHER_NB - 1) / GATHER_NB;
    int start = nbid * span;
    int end = min(start + span, total);
    int lane = threadIdx.x & 31;
    int sub = threadIdx.x >> 5;          // 8 point-slots per 256-thread block
    int co = lane * 4;
    for (int sidx = start + sub; sidx < end; sidx += 8) {
        float4 rec = sorted[sidx];
        int pack = __float_as_int(rec.x);
        int x0 = (pack & 0xffff) - 8;
        int y0 = (pack >> 16) - 8;
        float wx = rec.y, wy = rec.z;
        int point = __float_as_int(rec.w);
        int b = point / N;
        const float* base = fmT + (size_t)b * HF * WF * CC;
        // clamped indices + zeroed weights (matches reference clip + w*ok exactly)
        int xA = min(max(x0, 0), WF - 1), xB = min(max(x0 + 1, 0), WF - 1);
        int yA = min(max(y0, 0), HF - 1), yB = min(max(y0 + 1, 0), HF - 1);
        float okxA = (x0 >= 0 && x0 < WF) ? 1.0f : 0.0f;
        float okxB = (x0 + 1 >= 0 && x0 + 1 < WF) ? 1.0f : 0.0f;
        float okyA = (y0 >= 0 && y0 < HF) ? 1.0f : 0.0f;
        float okyB = (y0 + 1 >= 0 && y0 + 1 < HF) ? 1.0f : 0.0f;
        float w00 = (1.0f - wx) * (1.0f - wy) * okxA * okyA;
        float w10 = wx * (1.0f - wy) * okxB * okyA;
        float w01 = (1.0f - wx) * wy * okxA * okyB;
        float w11 = wx * wy * okxB * okyB;
        const f4* p00 = (const f4*)(base + ((size_t)yA * WF + xA) * CC + co);
        const f4* p10 = (const f4*)(base + ((size_t)yA * WF + xB) * CC + co);
        const f4* p01 = (const f4*)(base + ((size_t)yB * WF + xA) * CC + co);
        const f4* p11 = (const f4*)(base + ((size_t)yB * WF + xB) * CC + co);
        f4 v00 = *p00, v10 = *p10, v01 = *p01, v11 = *p11;
        f4 acc = v00 * w00 + v10 * w10 + v01 * w01 + v11 * w11;
        __builtin_nontemporal_store(acc, (f4*)out + (size_t)point * (CC / 4) + lane);
    }
}

extern "C" void kernel_launch(void* const* d_in, const int* in_sizes, int n_in,
                              void* d_out, int out_size, void* d_ws, size_t ws_size,
                              hipStream_t stream) {
    const float* fm = (const float*)d_in[0];
    const float* v2d = (const float*)d_in[1];
    const float* v3d = (const float*)d_in[2];
    const int* parents = (const int*)d_in[3];
    const float* bary = (const float*)d_in[4];
    const int* pH = (const int*)d_in[5];
    const int* pW = (const int*)d_in[6];

    int Nv = in_sizes[1] / (BB * 2);
    int N = in_sizes[3] / 3;
    int K = in_sizes[4] / 3;

    // workspace layout (floats): fmT | depth | params | sorted | counts | sums
    float* fmT = (float*)d_ws;
    float* depth = fmT + (size_t)BB * CC * HF * WF;            // +8,388,608
    float* params = depth + (size_t)BB * 512 * 512;            // +1,048,576
    float* sorted = params + (size_t)BB * 200000 * 4;          // +3,200,000
    int* counts = (int*)(sorted + (size_t)BB * 200000 * 4);    // +3,200,000
    int* sums = counts + SCAN_M;                               // +250,880

    float* out_lf = (float*)d_out;
    float* out_vw = out_lf + (size_t)BB * N * CC;
    float* out_c3 = out_vw + (size_t)BB * N;

    hipLaunchKernelGGL(transpose_fm, dim3(HF * WF / 32, CC / 32, BB), dim3(32, 8), 0, stream,
                       fm, fmT, depth);
    hipLaunchKernelGGL(depth_scatter, dim3((BB * Nv + 255) / 256), dim3(256), 0, stream,
                       v2d, v3d, depth, Nv, pH, pW);
    hipLaunchKernelGGL(setup_hist, dim3(NBLK), dim3(512), 0, stream,
                       v2d, v3d, parents, bary, depth, out_vw, out_c3, (float4*)params, counts,
                       N, Nv, K, pH, pW);
    hipLaunchKernelGGL(scan1, dim3(NCHUNK), dim3(1024), 0, stream, counts, sums);
    hipLaunchKernelGGL(scan3, dim3(NCHUNK), dim3(1024), 0, stream, counts, sums);
    hipLaunchKernelGGL(scatter_sorted, dim3(NBLK), dim3(512), 0, stream,
                       (const float4*)params, counts, (float4*)sorted, N);
    hipLaunchKernelGGL(gather_feats, dim3(GATHER_NB), dim3(256), 0, stream,
                       fmT, (const float4*)sorted, out_lf, N);
}

// Round 7
// 146.878 us; speedup vs baseline: 1.0997x; 1.0997x over previous
//
#include <hip/hip_runtime.h>
#include <math.h>

#define BB 4
#define CC 128
#define HF 128
#define WF 128
#define GATHER_NB 2048   // 8 groups x 256 blocks

typedef float f4 __attribute__((ext_vector_type(4)));

// ---------- helpers with fp-contract OFF to bit-match the numpy reference ----------
__device__ __forceinline__ float wsum3(float a, float wa, float b, float wb, float c, float wc) {
#pragma clang fp contract(off)
    {
        float r = a * wa;
        r = r + b * wb;
        r = r + c * wc;
        return r;
    }
}

__device__ __forceinline__ float to_pix(float cv, int Wm1, int WFm1) {
#pragma clang fp contract(off)
    {
        float g = cv / (float)Wm1 * 2.0f - 1.0f;
        return (g + 1.0f) * 0.5f * (float)WFm1;
    }
}

// ---------- 1. NCHW -> NHWC transpose of feature_map, fused with depth init ----------
__global__ void transpose_fm(const float* __restrict__ fm, float* __restrict__ fmT,
                             float* __restrict__ depth) {
    __shared__ float tile[32][33];
    int b = blockIdx.z;
    int hw0 = blockIdx.x * 32;
    int c0 = blockIdx.y * 32;
    int tx = threadIdx.x;
    int ty = threadIdx.y;
    // fused depth-buffer init: 8192 blocks x 256 threads cover the 1,048,576 texels
    int gid = (((blockIdx.z * gridDim.y + blockIdx.y) * gridDim.x + blockIdx.x) << 8) +
              (ty << 5) + tx;
    if (gid < BB * 512 * 512) depth[gid] = INFINITY;
    const float* in = fm + (size_t)b * CC * HF * WF;
    float* out = fmT + (size_t)b * HF * WF * CC;
    #pragma unroll
    for (int i = ty; i < 32; i += 8)
        tile[i][tx] = in[(size_t)(c0 + i) * (HF * WF) + hw0 + tx];
    __syncthreads();
    #pragma unroll
    for (int i = ty; i < 32; i += 8)
        out[(size_t)(hw0 + i) * CC + c0 + tx] = tile[tx][i];
}

// ---------- 2. scatter-min of vertex depths ----------
__global__ void depth_scatter(const float* __restrict__ v2d, const float* __restrict__ v3d,
                              float* __restrict__ depth, int Nv, const int* pH, const int* pW) {
    int H = *pH, W = *pW;
    int i = blockIdx.x * blockDim.x + threadIdx.x;
    if (i >= BB * Nv) return;
    int b = i / Nv, v = i - b * Nv;
    float x = v2d[((size_t)b * Nv + v) * 2 + 0];
    float y = v2d[((size_t)b * Nv + v) * 2 + 1];
    int xv = (int)rintf(x);
    int yv = (int)rintf(y);
    if (xv < 0 || xv >= W || yv < 0 || yv >= H) return;
    float z = v3d[((size_t)b * Nv + v) * 3 + 2];
    // z > 0 always, inf init: int compare == float compare for non-negative floats
    atomicMin((int*)&depth[(size_t)b * H * W + (size_t)yv * W + xv], __float_as_int(z));
}

// ---------- 3. per-point setup (no sort) ----------
__global__ void __launch_bounds__(256)
point_setup(const float* __restrict__ v2d, const float* __restrict__ v3d,
            const int* __restrict__ parents, const float* __restrict__ bary,
            const float* __restrict__ depth,
            float* __restrict__ out_vw, float* __restrict__ out_c3,
            float4* __restrict__ params,
            int N, int Nv, int K, const int* pH, const int* pW) {
    int H = *pH, W = *pW;
    int idx = blockIdx.x * blockDim.x + threadIdx.x;
    if (idx >= BB * N) return;
    int b = idx / N, n = idx - b * N;
    int k = n % K;
    float w0 = bary[k * 3 + 0], w1 = bary[k * 3 + 1], w2 = bary[k * 3 + 2];
    int i0 = parents[(size_t)n * 3 + 0];
    int i1 = parents[(size_t)n * 3 + 1];
    int i2 = parents[(size_t)n * 3 + 2];
    const float* v2b = v2d + (size_t)b * Nv * 2;
    const float* v3b = v3d + (size_t)b * Nv * 3;
    float ax = v2b[(size_t)i0 * 2], ay = v2b[(size_t)i0 * 2 + 1];
    float bx = v2b[(size_t)i1 * 2], by = v2b[(size_t)i1 * 2 + 1];
    float cx = v2b[(size_t)i2 * 2], cy = v2b[(size_t)i2 * 2 + 1];
    float c2x = wsum3(ax, w0, bx, w1, cx, w2);
    float c2y = wsum3(ay, w0, by, w1, cy, w2);
    float a0 = v3b[(size_t)i0 * 3], a1 = v3b[(size_t)i0 * 3 + 1], a2 = v3b[(size_t)i0 * 3 + 2];
    float b0 = v3b[(size_t)i1 * 3], b1 = v3b[(size_t)i1 * 3 + 1], b2 = v3b[(size_t)i1 * 3 + 2];
    float c0 = v3b[(size_t)i2 * 3], c1 = v3b[(size_t)i2 * 3 + 1], c2 = v3b[(size_t)i2 * 3 + 2];
    float c3x = wsum3(a0, w0, b0, w1, c0, w2);
    float c3y = wsum3(a1, w0, b1, w1, c1, w2);
    float c3z = wsum3(a2, w0, b2, w1, c2, w2);
    float e1x = b0 - a0, e1y = b1 - a1, e1z = b2 - a2;
    float e2x = c0 - a0, e2y = c1 - a1, e2z = c2 - a2;
    float nx = e1y * e2z - e1z * e2y;
    float ny = e1z * e2x - e1x * e2z;
    float nz = e1x * e2y - e1y * e2x;
    float nn = sqrtf(nx * nx + ny * ny + nz * nz) + 1e-8f;
    nx /= nn; ny /= nn; nz /= nn;
    float vn = sqrtf(c3x * c3x + c3y * c3y + c3z * c3z) + 1e-8f;
    float vx = -c3x / vn, vy = -c3y / vn, vz = -c3z / vn;
    float ang = fmaxf(nx * vx + ny * vy + nz * vz, 0.0f);
    int xc = (int)rintf(c2x); xc = min(max(xc, 0), W - 1);
    int yc = (int)rintf(c2y); yc = min(max(yc, 0), H - 1);
    float dsamp = depth[(size_t)b * H * W + (size_t)yc * W + xc];
    bool visible = (c3z <= dsamp + 1e-3f) || isinf(dsamp);
    out_vw[idx] = visible ? ang : 0.0f;
    out_c3[(size_t)idx * 3 + 0] = c3x;
    out_c3[(size_t)idx * 3 + 1] = c3y;
    out_c3[(size_t)idx * 3 + 2] = c3z;
    float px = to_pix(c2x, W - 1, WF - 1);
    float py = to_pix(c2y, H - 1, HF - 1);
    float x0f = floorf(px), y0f = floorf(py);
    float4 p;
    p.x = __int_as_float((int)x0f);
    p.y = __int_as_float((int)y0f);
    p.z = px - x0f;
    p.w = py - y0f;
    params[idx] = p;
}

// ---------- 4. channel-split gather: idx-order writes, L2-resident half-slab reads ----
// 8 groups = (batch, channel-half); group = blockIdx & 7 pins each group to one XCD
// (consecutive blockIdx round-robin XCDs). Each XCD's working set = 4 MB = its L2.
__global__ void __launch_bounds__(256)
gather_feats(const float* __restrict__ fmT, const float4* __restrict__ params,
             float* __restrict__ out, int N) {
    int group = blockIdx.x & 7;       // -> XCD
    int off = blockIdx.x >> 3;        // 0..255 within group
    int b = group >> 1;               // batch
    int h = group & 1;                // channel half
    int span = (N + 255) >> 8;        // points per block
    int start = off * span;
    int end = min(start + span, N);
    int lane = threadIdx.x & 15;      // 16 lanes x 4 ch = 64 channels
    int slot = threadIdx.x >> 4;      // 16 point-slots per block
    int co = h * 64 + lane * 4;
    const float* base = fmT + (size_t)b * HF * WF * CC;
    const float4* pbase = params + (size_t)b * N;
    f4* obase = (f4*)out + (size_t)b * N * (CC / 4);
    for (int n = start + slot; n < end; n += 16) {
        float4 p = pbase[n];
        int x0 = __float_as_int(p.x);
        int y0 = __float_as_int(p.y);
        float wx = p.z, wy = p.w;
        // clamped indices + zeroed weights (matches reference clip + w*ok exactly)
        int xA = min(max(x0, 0), WF - 1), xB = min(max(x0 + 1, 0), WF - 1);
        int yA = min(max(y0, 0), HF - 1), yB = min(max(y0 + 1, 0), HF - 1);
        float okxA = (x0 >= 0 && x0 < WF) ? 1.0f : 0.0f;
        float okxB = (x0 + 1 >= 0 && x0 + 1 < WF) ? 1.0f : 0.0f;
        float okyA = (y0 >= 0 && y0 < HF) ? 1.0f : 0.0f;
        float okyB = (y0 + 1 >= 0 && y0 + 1 < HF) ? 1.0f : 0.0f;
        float w00 = (1.0f - wx) * (1.0f - wy) * okxA * okyA;
        float w10 = wx * (1.0f - wy) * okxB * okyA;
        float w01 = (1.0f - wx) * wy * okxA * okyB;
        float w11 = wx * wy * okxB * okyB;
        const f4* p00 = (const f4*)(base + ((size_t)yA * WF + xA) * CC + co);
        const f4* p10 = (const f4*)(base + ((size_t)yA * WF + xB) * CC + co);
        const f4* p01 = (const f4*)(base + ((size_t)yB * WF + xA) * CC + co);
        const f4* p11 = (const f4*)(base + ((size_t)yB * WF + xB) * CC + co);
        f4 v00 = *p00, v10 = *p10, v01 = *p01, v11 = *p11;
        f4 acc = v00 * w00 + v10 * w10 + v01 * w01 + v11 * w11;
        __builtin_nontemporal_store(acc, obase + (size_t)n * (CC / 4) + h * 16 + lane);
    }
}

extern "C" void kernel_launch(void* const* d_in, const int* in_sizes, int n_in,
                              void* d_out, int out_size, void* d_ws, size_t ws_size,
                              hipStream_t stream) {
    const float* fm = (const float*)d_in[0];
    const float* v2d = (const float*)d_in[1];
    const float* v3d = (const float*)d_in[2];
    const int* parents = (const int*)d_in[3];
    const float* bary = (const float*)d_in[4];
    const int* pH = (const int*)d_in[5];
    const int* pW = (const int*)d_in[6];

    int Nv = in_sizes[1] / (BB * 2);
    int N = in_sizes[3] / 3;
    int K = in_sizes[4] / 3;

    // workspace layout (floats): fmT | depth | params
    float* fmT = (float*)d_ws;
    float* depth = fmT + (size_t)BB * CC * HF * WF;            // +8,388,608
    float* params = depth + (size_t)BB * 512 * 512;            // +1,048,576

    float* out_lf = (float*)d_out;
    float* out_vw = out_lf + (size_t)BB * N * CC;
    float* out_c3 = out_vw + (size_t)BB * N;

    hipLaunchKernelGGL(transpose_fm, dim3(HF * WF / 32, CC / 32, BB), dim3(32, 8), 0, stream,
                       fm, fmT, depth);
    hipLaunchKernelGGL(depth_scatter, dim3((BB * Nv + 255) / 256), dim3(256), 0, stream,
                       v2d, v3d, depth, Nv, pH, pW);
    hipLaunchKernelGGL(point_setup, dim3((BB * N + 255) / 256), dim3(256), 0, stream,
                       v2d, v3d, parents, bary, depth, out_vw, out_c3, (float4*)params,
                       N, Nv, K, pH, pW);
    hipLaunchKernelGGL(gather_feats, dim3(GATHER_NB), dim3(256), 0, stream,
                       fmT, (const float4*)params, out_lf, N);
}